// Round 1
// baseline (455.799 us; speedup 1.0000x reference)
//
#include <hip/hip_runtime.h>
#include <math.h>

#define EMBED 1536
#define BN 64
#define XS_STRIDE 1544   // shorts; row stride 3088 B -> 16B aligned, 772%32=4 dwords (no 16-way LDS conflict)
#define GS_STRIDE 80     // shorts; row stride 160 B -> 16B aligned

typedef __attribute__((ext_vector_type(8))) short short8;
typedef __attribute__((ext_vector_type(4))) float f32x4;

__device__ inline unsigned short f2bf(float f) {
    union { float f; unsigned u; } c; c.f = f;
    unsigned u = c.u;
    return (unsigned short)((u + 0x7fffu + ((u >> 16) & 1u)) >> 16);
}
__device__ inline float bf2f(unsigned short h) {
    union { unsigned u; float f; } c; c.u = ((unsigned)h) << 16;
    return c.f;
}

// Prep (one kernel): wdg[b][d]=bf16(w_down*gamma), wub=bf16(w_up), c1/c2 reductions.
__global__ void prep_kernel(const float* __restrict__ w_down, const float* __restrict__ w_up,
                            const float* __restrict__ gamma, const float* __restrict__ beta,
                            unsigned short* __restrict__ wdg, unsigned short* __restrict__ wub,
                            float* __restrict__ c1, float* __restrict__ c2) {
    int blk = blockIdx.x;
    if (blk < 384) {
        int i = blk * 256 + threadIdx.x;          // < 64*1536
        int d = i % EMBED;
        wdg[i] = f2bf(w_down[i] * gamma[d]);      // fold LN gamma into down-weights
        wub[i] = f2bf(w_up[i]);
        return;
    }
    int b = blk - 384;                            // 0..63
    int t = threadIdx.x;
    float s1 = 0.f, s2 = 0.f;
    for (int d = t; d < EMBED; d += 256) {
        float w = w_down[b * EMBED + d];
        s1 += gamma[d] * w;
        s2 += beta[d] * w;
    }
    #pragma unroll
    for (int m = 1; m < 64; m <<= 1) { s1 += __shfl_xor(s1, m); s2 += __shfl_xor(s2, m); }
    __shared__ float r1[4], r2[4];
    int wave = t >> 6, lane = t & 63;
    if (lane == 0) { r1[wave] = s1; r2[wave] = s2; }
    __syncthreads();
    if (t == 0) {
        c1[b] = r1[0] + r1[1] + r1[2] + r1[3];
        c2[b] = r2[0] + r2[1] + r2[2] + r2[3];
    }
}

// Fused: LN-stats + down-proj(MFMA) + GELU + up-proj(MFMA) + L2-normalize.
// 16 rows/block, 512 threads (8 waves). LDS ~52 KB -> 3 blocks/CU = 24 waves/CU (6/SIMD).
// Register budget 512/6 = 85: GEMM2 is register-free (two-pass recompute, no cc[] array).
__global__ __launch_bounds__(512, 6) void fused_kernel(
    const float* __restrict__ x, const float* __restrict__ b_down,
    const float* __restrict__ b_up,
    const unsigned short* __restrict__ wdg, const unsigned short* __restrict__ wub,
    const float* __restrict__ c1, const float* __restrict__ c2,
    float* __restrict__ out)
{
    __shared__ unsigned short xs[16 * XS_STRIDE];  // bf16(x): GEMM1 A-operand AND GEMM2 residual
    __shared__ unsigned short gs[16 * GS_STRIDE];  // bf16 gelu output [token][b]
    __shared__ float mean_s[16], rstd_s[16], sumsq_s[16];

    const int tid  = threadIdx.x;
    const int wave = tid >> 6, lane = tid & 63;
    const int l16  = lane & 15, quad = lane >> 4;
    const long row0 = (long)blockIdx.x * 16;

    // ---- Phase A: 2 rows/wave (12 outstanding float4 loads = 48 regs), stats, stage bf16(x) ----
    {
        float4 v[2][6];
        #pragma unroll
        for (int j = 0; j < 2; ++j) {
            const float4* xp = (const float4*)(x + (row0 + wave * 2 + j) * EMBED);
            #pragma unroll
            for (int k = 0; k < 6; ++k) v[j][k] = xp[lane + 64 * k];
        }
        #pragma unroll
        for (int j = 0; j < 2; ++j) {
            int lr = wave * 2 + j;
            float s = 0.f, ss = 0.f;
            #pragma unroll
            for (int k = 0; k < 6; ++k) {
                s  += v[j][k].x + v[j][k].y + v[j][k].z + v[j][k].w;
                ss += v[j][k].x * v[j][k].x + v[j][k].y * v[j][k].y
                    + v[j][k].z * v[j][k].z + v[j][k].w * v[j][k].w;
            }
            #pragma unroll
            for (int m = 1; m < 64; m <<= 1) { s += __shfl_xor(s, m); ss += __shfl_xor(ss, m); }
            float mean = s * (1.f / EMBED);
            float var  = ss * (1.f / EMBED) - mean * mean;
            if (lane == 0) {
                mean_s[lr] = mean;
                rstd_s[lr] = rsqrtf(var + 1e-5f);
                sumsq_s[lr] = 0.f;
            }
            #pragma unroll
            for (int k = 0; k < 6; ++k) {
                ushort4 p;
                p.x = f2bf(v[j][k].x); p.y = f2bf(v[j][k].y);
                p.z = f2bf(v[j][k].z); p.w = f2bf(v[j][k].w);
                *(ushort4*)(&xs[lr * XS_STRIDE + 4 * (lane + 64 * k)]) = p;
            }
        }
    }
    __syncthreads();

    // ---- GEMM1 (waves 0-3): t[token 16][b 16/wave] = x . (gamma*w_down)^T, K=1536 ----
    if (wave < 4) {
        f32x4 acc = {0.f, 0.f, 0.f, 0.f};
        {
            const unsigned short* arow = &xs[l16 * XS_STRIDE];                    // A[m=l16][k]
            const unsigned short* brow = wdg + (size_t)(wave * 16 + l16) * EMBED; // B^T: W[b=l16][k]
            #pragma unroll 4
            for (int kk = 0; kk < 48; ++kk) {
                int ko = kk * 32 + quad * 8;
                short8 a = *(const short8*)(arow + ko);
                short8 b = *(const short8*)(brow + ko);
                acc = __builtin_amdgcn_mfma_f32_16x16x32_bf16(a, b, acc, 0, 0, 0);
            }
        }
        // epilogue: LN scalar corrections + bias + exact GELU -> gs[token][b]
        {
            int bg = wave * 16 + l16;  // D col = lane&15
            float c1v = c1[bg], c2v = c2[bg], bdv = b_down[bg];
            #pragma unroll
            for (int reg = 0; reg < 4; ++reg) {
                int r = quad * 4 + reg;  // D row = (lane>>4)*4 + reg
                float rs = rstd_s[r];
                float v = rs * acc[reg] - rs * mean_s[r] * c1v + c2v + bdv;
                float g = 0.5f * v * (1.f + erff(v * 0.70710678118654752f));
                gs[r * GS_STRIDE + bg] = f2bf(g);
            }
        }
    }
    __syncthreads();

    // ---- GEMM2 (transposed tile): D[m=d 16][n=token 16] = w_up_tile . g^T + (x + b_up) ----
    // Each of 8 waves owns 192 d-cols = 12 tiles. Pass 1 computes c only to accumulate sumsq
    // (values discarded -> no cc[] live range, regs stay under the 85 budget). Pass 2 recomputes
    // the bit-identical c and stores the normalized result.
    short8 gb0 = *(const short8*)(&gs[l16 * GS_STRIDE + quad * 8]);
    short8 gb1 = *(const short8*)(&gs[l16 * GS_STRIDE + 32 + quad * 8]);
    const int dbase = wave * 192;
    float sqs = 0.f;
    #pragma unroll 4
    for (int t = 0; t < 12; ++t) {
        int d0 = dbase + t * 16;
        int dm = d0 + quad * 4;                                  // C rows: 4 consecutive d
        float4 bu = *(const float4*)(b_up + dm);
        ushort4 rx = *(const ushort4*)(&xs[l16 * XS_STRIDE + dm]); // residual: token l16
        f32x4 c;
        c[0] = bf2f(rx.x) + bu.x;
        c[1] = bf2f(rx.y) + bu.y;
        c[2] = bf2f(rx.z) + bu.z;
        c[3] = bf2f(rx.w) + bu.w;
        const unsigned short* wrow = wub + (size_t)(d0 + l16) * 64;  // A[m=l16][k] = w_up[d0+l16][k]
        short8 a0 = *(const short8*)(wrow + quad * 8);
        short8 a1 = *(const short8*)(wrow + 32 + quad * 8);
        c = __builtin_amdgcn_mfma_f32_16x16x32_bf16(a0, gb0, c, 0, 0, 0);
        c = __builtin_amdgcn_mfma_f32_16x16x32_bf16(a1, gb1, c, 0, 0, 0);
        sqs += c[0] * c[0] + c[1] * c[1] + c[2] * c[2] + c[3] * c[3];
    }
    // per-token sumsq: lane's partial is for token l16 over this wave's 192 d; sum over quads,
    // then one LDS atomic per (wave, token).
    sqs += __shfl_xor(sqs, 16);
    sqs += __shfl_xor(sqs, 32);
    if (lane < 16) atomicAdd(&sumsq_s[l16], sqs);
    __syncthreads();

    const float inv = 1.f / fmaxf(sqrtf(sumsq_s[l16]), 1e-12f);
    float* orow = out + (row0 + l16) * EMBED;
    #pragma unroll 4
    for (int t = 0; t < 12; ++t) {
        int d0 = dbase + t * 16;
        int dm = d0 + quad * 4;
        float4 bu = *(const float4*)(b_up + dm);
        ushort4 rx = *(const ushort4*)(&xs[l16 * XS_STRIDE + dm]);
        f32x4 c;
        c[0] = bf2f(rx.x) + bu.x;
        c[1] = bf2f(rx.y) + bu.y;
        c[2] = bf2f(rx.z) + bu.z;
        c[3] = bf2f(rx.w) + bu.w;
        const unsigned short* wrow = wub + (size_t)(d0 + l16) * 64;
        short8 a0 = *(const short8*)(wrow + quad * 8);
        short8 a1 = *(const short8*)(wrow + 32 + quad * 8);
        c = __builtin_amdgcn_mfma_f32_16x16x32_bf16(a0, gb0, c, 0, 0, 0);
        c = __builtin_amdgcn_mfma_f32_16x16x32_bf16(a1, gb1, c, 0, 0, 0);
        float4 o;
        o.x = c[0] * inv; o.y = c[1] * inv; o.z = c[2] * inv; o.w = c[3] * inv;
        *(float4*)(orow + dm) = o;   // 16 B/lane store, 64 B contiguous per row per instr
    }
}

extern "C" void kernel_launch(void* const* d_in, const int* in_sizes, int n_in,
                              void* d_out, int out_size, void* d_ws, size_t ws_size,
                              hipStream_t stream)
{
    const float* x      = (const float*)d_in[0];
    const float* w_down = (const float*)d_in[1];
    const float* b_down = (const float*)d_in[2];
    const float* w_up   = (const float*)d_in[3];
    const float* b_up   = (const float*)d_in[4];
    const float* gamma  = (const float*)d_in[5];
    const float* beta   = (const float*)d_in[6];
    float* out = (float*)d_out;

    const int N = in_sizes[0] / EMBED;  // 32768, multiple of 16

    unsigned short* wdg = (unsigned short*)d_ws;
    unsigned short* wub = wdg + BN * EMBED;
    float* c1 = (float*)(wub + BN * EMBED);
    float* c2 = c1 + BN;

    prep_kernel<<<384 + BN, 256, 0, stream>>>(w_down, w_up, gamma, beta, wdg, wub, c1, c2);
    fused_kernel<<<N / 16, 512, 0, stream>>>(x, b_down, b_up, wdg, wub, c1, c2, out);
}